// Round 1
// baseline (993.128 us; speedup 1.0000x reference)
//
#include <hip/hip_runtime.h>
#include <climits>
#include <stdint.h>

#define HH 1536
#define WW 2048
#define NPIX (HH*WW)        // 3145728
#define WSHIFT 11
#define WMASK 2047
#define BT 256
#define PPT 16

// ---------------- K1: threshold -> flags (bit0 = comb, bit1 = text) ----------
__global__ void k_flags(const float4* __restrict__ xv, uchar4* __restrict__ flags4) {
    int t = blockIdx.x * blockDim.x + threadIdx.x;   // one thread per 4 pixels
    if (t >= NPIX / 4) return;
    float4 a = xv[t * 2 + 0];   // pixels p0=(x,y) p1=(z,w)
    float4 b = xv[t * 2 + 1];   // pixels p2=(x,y) p3=(z,w)
    uchar4 o;
    {
        unsigned tx = a.x > 0.4f, lk = a.y > 0.4f;
        o.x = (unsigned char)((tx | lk) | (tx << 1));
    }
    {
        unsigned tx = a.z > 0.4f, lk = a.w > 0.4f;
        o.y = (unsigned char)((tx | lk) | (tx << 1));
    }
    {
        unsigned tx = b.x > 0.4f, lk = b.y > 0.4f;
        o.z = (unsigned char)((tx | lk) | (tx << 1));
    }
    {
        unsigned tx = b.z > 0.4f, lk = b.w > 0.4f;
        o.w = (unsigned char)((tx | lk) | (tx << 1));
    }
    flags4[t] = o;
}

// ---------------- K2: 3x3 binary dilation -> fg (bit2); labels[i] = i --------
__global__ void k_dilate_init(unsigned char* __restrict__ flags, int* __restrict__ labels) {
    int i = blockIdx.x * blockDim.x + threadIdx.x;
    if (i >= NPIX) return;
    int r = i >> WSHIFT, c = i & WMASK;
    unsigned f = flags[i];
    unsigned fg = 0;
    for (int dr = -1; dr <= 1; ++dr) {
        int rr = r + dr;
        if ((unsigned)rr >= (unsigned)HH) continue;
        int base = rr << WSHIFT;
        for (int dc = -1; dc <= 1; ++dc) {
            int cc = c + dc;
            if ((unsigned)cc >= (unsigned)WW) continue;
            fg |= (unsigned)(flags[base + cc] & 1u);
        }
    }
    labels[i] = i;
    if (fg) flags[i] = (unsigned char)(f | 4u);
}

// ---------------- UF merge (Playne-Hawick lock-free atomicMin union) ---------
__device__ __forceinline__ void merge_uf(int* L, int a, int b) {
    while (true) {
        int t;
        while ((t = L[a]) != a) a = t;   // walk to root (reads only)
        while ((t = L[b]) != b) b = t;
        if (a == b) return;
        if (a < b) { int s = a; a = b; b = s; }   // a > b
        int old = atomicMin(&L[a], b);
        if (old == a) return;            // attached root a under b
        a = old;                         // lost race or displaced a link: re-merge
    }
}

// ---------------- K3: union left & up edges for fg pixels --------------------
__global__ void k_merge(int* __restrict__ labels, const unsigned char* __restrict__ flags) {
    int i = blockIdx.x * blockDim.x + threadIdx.x;
    if (i >= NPIX) return;
    if (!(flags[i] & 4u)) return;
    if ((i & WMASK) && (flags[i - 1] & 4u)) merge_uf(labels, i, i - 1);
    if (i >= WW && (flags[i - WW] & 4u)) merge_uf(labels, i, i - WW);
}

// ---------------- find with path halving + full compress (safe post-merge) ---
__device__ __forceinline__ int find_c(int* L, int i) {
    int x = L[i];
    if (x == i) return i;
    while (true) {
        int p = L[x];
        if (p == x) break;
        int gp = L[p];
        L[x] = gp;       // benign race: always a valid ancestor, monotone toward root
        x = gp;
    }
    L[i] = x;
    return x;
}

// ---------------- K4/5 fused: compress, mark roots (bit3), bbox accumulate ---
__global__ void k_find_acc(int* __restrict__ labels, unsigned char* __restrict__ flags,
                           int* __restrict__ ymin, int* __restrict__ xmin,
                           int* __restrict__ ymax, int* __restrict__ xmax,
                           int* __restrict__ hastext) {
    __shared__ int shR0;
    __shared__ int sw[4][5];
    int t = threadIdx.x;
    int base = blockIdx.x * (BT * PPT);

    if (t == 0) {
        int r0 = -1;
        for (int k = 0; k < PPT; ++k) {
            int p = base + k * BT;
            if (flags[p] & 4u) { r0 = find_c(labels, p); break; }
        }
        shR0 = r0;
    }
    __syncthreads();
    int R0 = shR0;

    int rmin = INT_MAX, rmax = -1, cmin = INT_MAX, cmax = -1, txt = 0;
    for (int k = 0; k < PPT; ++k) {
        int p = base + k * BT + t;
        unsigned f = flags[p];
        if (!(f & 4u)) continue;
        int root = find_c(labels, p);
        if (root == p) flags[p] = (unsigned char)(f | 8u);   // owner-only write
        int r = p >> WSHIFT, c = p & WMASK;
        int tx = (int)((f >> 1) & 1u);
        if (root == R0) {
            rmin = min(rmin, r); rmax = max(rmax, r);
            cmin = min(cmin, c); cmax = max(cmax, c);
            txt |= tx;
        } else {   // rare: off-dominant component
            atomicMin(&ymin[root], r); atomicMax(&ymax[root], r);
            atomicMin(&xmin[root], c); atomicMax(&xmax[root], c);
            if (tx) hastext[root] = 1;   // 0->1 only; plain store is safe
        }
    }

    // wave (64-lane) butterfly reduce
    #pragma unroll
    for (int o = 32; o > 0; o >>= 1) {
        rmin = min(rmin, __shfl_xor(rmin, o));
        rmax = max(rmax, __shfl_xor(rmax, o));
        cmin = min(cmin, __shfl_xor(cmin, o));
        cmax = max(cmax, __shfl_xor(cmax, o));
        txt |= __shfl_xor(txt, o);
    }
    int wv = t >> 6;
    if ((t & 63) == 0) {
        sw[wv][0] = rmin; sw[wv][1] = rmax; sw[wv][2] = cmin; sw[wv][3] = cmax; sw[wv][4] = txt;
    }
    __syncthreads();
    if (t == 0 && R0 >= 0) {
        for (int w2 = 1; w2 < 4; ++w2) {
            rmin = min(rmin, sw[w2][0]); rmax = max(rmax, sw[w2][1]);
            cmin = min(cmin, sw[w2][2]); cmax = max(cmax, sw[w2][3]);
            txt |= sw[w2][4];
        }
        if (rmax >= 0) {
            atomicMin(&ymin[R0], rmin); atomicMax(&ymax[R0], rmax);
            atomicMin(&xmin[R0], cmin); atomicMax(&xmax[R0], cmax);
            if (txt) hastext[R0] = 1;
        }
    }
}

// ---------------- K6: emit bboxes (N,4) int32 + valid (N,) int32 -------------
__global__ void k_output(const unsigned char* __restrict__ flags,
                         const int* __restrict__ ymin, const int* __restrict__ xmin,
                         const int* __restrict__ ymax, const int* __restrict__ xmax,
                         const int* __restrict__ hastext,
                         int4* __restrict__ obb, int* __restrict__ oval) {
    int i = blockIdx.x * blockDim.x + threadIdx.x;
    if (i >= NPIX) return;
    unsigned f = flags[i];
    int4 bb = make_int4(0, 0, 0, 0);
    int v = 0;
    if (f & 8u) {   // i is a component root (min flat index, count>0)
        int a = ymin[i], b = ymax[i], c = xmin[i], d = xmax[i];
        int h = b - a, w = d - c;
        if (h > 4 && w > 4 && hastext[i]) { bb = make_int4(a, c, h, w); v = 1; }
    }
    obb[i] = bb;
    oval[i] = v;
}

extern "C" void kernel_launch(void* const* d_in, const int* in_sizes, int n_in,
                              void* d_out, int out_size, void* d_ws, size_t ws_size,
                              hipStream_t stream) {
    const float* x = (const float*)d_in[0];

    // ws layout: labels | ymin | xmin | ymax | xmax | hastext | flags  (25N B)
    int* labels  = (int*)d_ws;
    int* ymin    = labels + NPIX;
    int* xmin    = ymin + NPIX;
    int* ymax    = xmin + NPIX;
    int* xmax    = ymax + NPIX;
    int* hastext = xmax + NPIX;
    unsigned char* flags = (unsigned char*)(hastext + NPIX);

    // init: mins -> 0x7F7F7F7F (big), maxes/hastext -> 0
    hipMemsetAsync(ymin, 0x7F, (size_t)NPIX * 8, stream);
    hipMemsetAsync(ymax, 0x00, (size_t)NPIX * 12, stream);

    k_flags<<<NPIX / 4 / 256, 256, 0, stream>>>((const float4*)x, (uchar4*)flags);
    k_dilate_init<<<NPIX / 256, 256, 0, stream>>>(flags, labels);
    k_merge<<<NPIX / 256, 256, 0, stream>>>(labels, flags);
    k_find_acc<<<NPIX / (BT * PPT), BT, 0, stream>>>(labels, flags, ymin, xmin, ymax, xmax, hastext);

    int* obb  = (int*)d_out;
    int* oval = obb + (size_t)NPIX * 4;
    k_output<<<NPIX / 256, 256, 0, stream>>>(flags, ymin, xmin, ymax, xmax, hastext,
                                             (int4*)obb, oval);
}

// Round 2
// 221.571 us; speedup vs baseline: 4.4822x; 4.4822x over previous
//
#include <hip/hip_runtime.h>
#include <climits>
#include <stdint.h>

#define HH 1536
#define WW 2048
#define NPIX (HH*WW)        // 3145728
#define WSHIFT 11
#define WMASK 2047
#define BT 256
#define PPT 16
#define TBX 64              // tile cols (2048/32)
#define TBY 48              // tile rows (1536/32)
#define EV (63*1536)        // vertical tile-boundary edges
#define EH (47*2048)        // horizontal tile-boundary edges

// ---------------- K1: threshold -> flags (bit0 = comb, bit1 = text) ----------
__global__ void k_flags(const float4* __restrict__ xv, uchar4* __restrict__ flags4) {
    int t = blockIdx.x * blockDim.x + threadIdx.x;   // one thread per 4 pixels
    if (t >= NPIX / 4) return;
    float4 a = xv[t * 2 + 0];
    float4 b = xv[t * 2 + 1];
    uchar4 o;
    { unsigned tx = a.x > 0.4f, lk = a.y > 0.4f; o.x = (unsigned char)((tx | lk) | (tx << 1)); }
    { unsigned tx = a.z > 0.4f, lk = a.w > 0.4f; o.y = (unsigned char)((tx | lk) | (tx << 1)); }
    { unsigned tx = b.x > 0.4f, lk = b.y > 0.4f; o.z = (unsigned char)((tx | lk) | (tx << 1)); }
    { unsigned tx = b.z > 0.4f, lk = b.w > 0.4f; o.w = (unsigned char)((tx | lk) | (tx << 1)); }
    flags4[t] = o;
}

// ---------------- LDS union-find merge (atomicMin on shared) -----------------
__device__ __forceinline__ void lmerge(int* L, int a, int b) {
    while (true) {
        int t;
        while ((t = L[a]) != a) a = t;
        while ((t = L[b]) != b) b = t;
        if (a == b) return;
        if (a < b) { int s = a; a = b; b = s; }
        int old = atomicMin(&L[a], b);
        if (old == a) return;
        a = old;
    }
}

// ---------------- K2: fused dilate + tile-local CCL (32x32 in LDS) -----------
// flags: read bit0 (comb) of 34x34 halo; write back (bits0,1 preserved) | fg<<2.
// Cross-block halo read vs interior write race is benign: writes only add bit2,
// halo readers consume bit0 only, byte stores are atomic.
__global__ __launch_bounds__(256) void k_local(unsigned char* flags, int* __restrict__ labels) {
    __shared__ unsigned char sc[34 * 35];
    __shared__ unsigned char sfg[32 * 32];
    __shared__ int L[32 * 32];
    int bx = blockIdx.x & (TBX - 1);
    int by = blockIdx.x / TBX;
    int c0 = bx * 32, r0 = by * 32;
    int t = threadIdx.x;

    for (int u = t; u < 34 * 34; u += 256) {
        int hr = u / 34, hc = u - hr * 34;
        int gr = r0 + hr - 1, gc = c0 + hc - 1;
        unsigned v = 0;
        if ((unsigned)gr < (unsigned)HH && (unsigned)gc < (unsigned)WW)
            v = flags[(gr << WSHIFT) + gc];
        sc[hr * 35 + hc] = (unsigned char)v;
    }
    __syncthreads();

    int lc = t & 31, lr0 = t >> 5;   // thread covers rows lr0+8k, k=0..3
    unsigned char myf[4]; int myfg[4];
    #pragma unroll
    for (int k = 0; k < 4; ++k) {
        int lr = lr0 + 8 * k;
        int s = (lr + 1) * 35 + (lc + 1);
        unsigned fg = (sc[s-36] | sc[s-35] | sc[s-34] |
                       sc[s-1]  | sc[s]   | sc[s+1]  |
                       sc[s+34] | sc[s+35] | sc[s+36]) & 1u;
        myf[k] = (unsigned char)((sc[s] & 3u) | (fg << 2));
        myfg[k] = (int)fg;
        int li = lr * 32 + lc;
        sfg[li] = (unsigned char)fg;
        L[li] = li;
    }
    __syncthreads();

    #pragma unroll
    for (int k = 0; k < 4; ++k) {
        if (!myfg[k]) continue;
        int lr = lr0 + 8 * k;
        int li = lr * 32 + lc;
        if (lc > 0 && sfg[li - 1])  lmerge(L, li, li - 1);
        if (lr > 0 && sfg[li - 32]) lmerge(L, li, li - 32);
    }
    __syncthreads();

    #pragma unroll
    for (int k = 0; k < 4; ++k) {
        int lr = lr0 + 8 * k;
        int li = lr * 32 + lc;
        int gi = ((r0 + lr) << WSHIFT) + c0 + lc;
        flags[gi] = myf[k];
        if (myfg[k]) {
            int x = li;
            while (L[x] != x) x = L[x];
            // local min-index root == global min flat index within tile
            labels[gi] = ((r0 + (x >> 5)) << WSHIFT) + c0 + (x & 31);
        }
    }
}

// ---------------- global UF merge (Playne-Hawick lock-free) ------------------
__device__ __forceinline__ void merge_uf(int* L, int a, int b) {
    while (true) {
        int t;
        while ((t = L[a]) != a) a = t;
        while ((t = L[b]) != b) b = t;
        if (a == b) return;
        if (a < b) { int s = a; a = b; b = s; }
        int old = atomicMin(&L[a], b);
        if (old == a) return;
        a = old;
    }
}

// ---------------- K3: merge across tile boundaries only, deduped -------------
// Skip an edge when the parallel edge one step back exists AND both rungs are
// intra-tile fg adjacencies (guaranteed merged by k_local) -> dedup chain
// terminates at the tile-row/col start, preserving connectivity.
__global__ void k_boundary(int* __restrict__ labels, const unsigned char* __restrict__ flags) {
    int tid = blockIdx.x * blockDim.x + threadIdx.x;
    if (tid < EV) {                       // vertical edge: (r,c-1)-(r,c), c=32*(b+1)
        int b = tid / 1536, r = tid - b * 1536;
        int c = (b + 1) * 32;
        int i = (r << WSHIFT) + c;
        unsigned fR = flags[i], fL = flags[i - 1];
        if (!((fR & fL) & 4u)) return;
        if (r & 31) {                     // prev pair in same tile row -> rungs are local
            unsigned gR = flags[i - WW], gL = flags[i - 1 - WW];
            if ((gR & gL) & 4u) return;
        }
        merge_uf(labels, i, i - 1);
    } else if (tid < EV + EH) {           // horizontal edge: (r-1,c)-(r,c), r=32*(bb+1)
        int u = tid - EV;
        int bb = u >> WSHIFT, c = u & WMASK;
        int r = (bb + 1) * 32;
        int i = (r << WSHIFT) + c;
        unsigned fD = flags[i], fU = flags[i - WW];
        if (!((fD & fU) & 4u)) return;
        if (c & 31) {                     // prev pair in same tile col -> rungs are local
            unsigned gD = flags[i - 1], gU = flags[i - 1 - WW];
            if ((gD & gU) & 4u) return;
        }
        merge_uf(labels, i, i - WW);
    }
}

// ---------------- find with path halving + full compress (safe post-merge) ---
__device__ __forceinline__ int find_c(int* L, int i) {
    int x = L[i];
    if (x == i) return i;
    while (true) {
        int p = L[x];
        if (p == x) break;
        int gp = L[p];
        L[x] = gp;       // benign race: always a valid ancestor
        x = gp;
    }
    L[i] = x;
    return x;
}

// ---------------- K4: compress, mark roots (bit3), bbox accumulate -----------
__global__ void k_find_acc(int* __restrict__ labels, unsigned char* __restrict__ flags,
                           int* __restrict__ ymin, int* __restrict__ xmin,
                           int* __restrict__ ymax, int* __restrict__ xmax,
                           int* __restrict__ hastext) {
    __shared__ int shR0;
    __shared__ int sw[4][5];
    int t = threadIdx.x;
    int base = blockIdx.x * (BT * PPT);

    if (t == 0) {
        int r0 = -1;
        for (int k = 0; k < PPT; ++k) {
            int p = base + k * BT;
            if (flags[p] & 4u) { r0 = find_c(labels, p); break; }
        }
        shR0 = r0;
    }
    __syncthreads();
    int R0 = shR0;

    int rmin = INT_MAX, rmax = -1, cmin = INT_MAX, cmax = -1, txt = 0;
    for (int k = 0; k < PPT; ++k) {
        int p = base + k * BT + t;
        unsigned f = flags[p];
        if (!(f & 4u)) continue;
        int root = find_c(labels, p);
        if (root == p) flags[p] = (unsigned char)(f | 8u);
        int r = p >> WSHIFT, c = p & WMASK;
        int tx = (int)((f >> 1) & 1u);
        if (root == R0) {
            rmin = min(rmin, r); rmax = max(rmax, r);
            cmin = min(cmin, c); cmax = max(cmax, c);
            txt |= tx;
        } else {
            atomicMin(&ymin[root], r); atomicMax(&ymax[root], r);
            atomicMin(&xmin[root], c); atomicMax(&xmax[root], c);
            if (tx) hastext[root] = 1;
        }
    }

    #pragma unroll
    for (int o = 32; o > 0; o >>= 1) {
        rmin = min(rmin, __shfl_xor(rmin, o));
        rmax = max(rmax, __shfl_xor(rmax, o));
        cmin = min(cmin, __shfl_xor(cmin, o));
        cmax = max(cmax, __shfl_xor(cmax, o));
        txt |= __shfl_xor(txt, o);
    }
    int wv = t >> 6;
    if ((t & 63) == 0) {
        sw[wv][0] = rmin; sw[wv][1] = rmax; sw[wv][2] = cmin; sw[wv][3] = cmax; sw[wv][4] = txt;
    }
    __syncthreads();
    if (t == 0 && R0 >= 0) {
        for (int w2 = 1; w2 < 4; ++w2) {
            rmin = min(rmin, sw[w2][0]); rmax = max(rmax, sw[w2][1]);
            cmin = min(cmin, sw[w2][2]); cmax = max(cmax, sw[w2][3]);
            txt |= sw[w2][4];
        }
        if (rmax >= 0) {
            atomicMin(&ymin[R0], rmin); atomicMax(&ymax[R0], rmax);
            atomicMin(&xmin[R0], cmin); atomicMax(&xmax[R0], cmax);
            if (txt) hastext[R0] = 1;
        }
    }
}

// ---------------- K5: emit bboxes (N,4) int32 + valid (N,) int32 -------------
__global__ void k_output(const unsigned char* __restrict__ flags,
                         const int* __restrict__ ymin, const int* __restrict__ xmin,
                         const int* __restrict__ ymax, const int* __restrict__ xmax,
                         const int* __restrict__ hastext,
                         int4* __restrict__ obb, int* __restrict__ oval) {
    int i = blockIdx.x * blockDim.x + threadIdx.x;
    if (i >= NPIX) return;
    unsigned f = flags[i];
    int4 bb = make_int4(0, 0, 0, 0);
    int v = 0;
    if (f & 8u) {
        int a = ymin[i], b = ymax[i], c = xmin[i], d = xmax[i];
        int h = b - a, w = d - c;
        if (h > 4 && w > 4 && hastext[i]) { bb = make_int4(a, c, h, w); v = 1; }
    }
    obb[i] = bb;
    oval[i] = v;
}

extern "C" void kernel_launch(void* const* d_in, const int* in_sizes, int n_in,
                              void* d_out, int out_size, void* d_ws, size_t ws_size,
                              hipStream_t stream) {
    const float* x = (const float*)d_in[0];

    // ws layout: labels | ymin | xmin | ymax | xmax | hastext | flags
    int* labels  = (int*)d_ws;
    int* ymin    = labels + NPIX;
    int* xmin    = ymin + NPIX;
    int* ymax    = xmin + NPIX;
    int* xmax    = ymax + NPIX;
    int* hastext = xmax + NPIX;
    unsigned char* flags = (unsigned char*)(hastext + NPIX);

    hipMemsetAsync(ymin, 0x7F, (size_t)NPIX * 8, stream);   // ymin,xmin -> big
    hipMemsetAsync(ymax, 0x00, (size_t)NPIX * 12, stream);  // ymax,xmax,hastext -> 0

    k_flags<<<NPIX / 4 / 256, 256, 0, stream>>>((const float4*)x, (uchar4*)flags);
    k_local<<<TBX * TBY, 256, 0, stream>>>(flags, labels);
    k_boundary<<<(EV + EH + 255) / 256, 256, 0, stream>>>(labels, flags);
    k_find_acc<<<NPIX / (BT * PPT), BT, 0, stream>>>(labels, flags, ymin, xmin, ymax, xmax, hastext);

    int* obb  = (int*)d_out;
    int* oval = obb + (size_t)NPIX * 4;
    k_output<<<NPIX / 256, 256, 0, stream>>>(flags, ymin, xmin, ymax, xmax, hastext,
                                             (int4*)obb, oval);
}